// Round 4
// baseline (120.039 us; speedup 1.0000x reference)
//
#include <hip/hip_runtime.h>
#include <hip/hip_bf16.h>

// LoRAModulatedSchnetInteraction: B=2, A=512, F=128, Rbf=64, R=4
// Strategy:
//  - Fold LoRA into per-batch effective weights: Weff[b] = W + A[b]@B[b]  (prep_weights)
//  - x_i: exact fp32 VALU dense (dense_ssp); final two atomwise layers fused (dense2_ssp)
//  - Core: fused per-(b,i,half) kernel: compact active j (mask), 3-layer bf16-MFMA MLP
//    on f_ij rows, * c_ij * x_i[j,:], masked sum over j -> partial y  (schnet_core)
//  - R4: weights held in VGPRs (loaded once, no per-GEMM L2 stalls); next-f-tile
//    register prefetch (hide ~900cy HBM gather); barriers 5->3 via h-buf ping-pong
//    and hazard-subsumed loop-end barrier; launch_bounds(256,3).

typedef float        f32x4  __attribute__((ext_vector_type(4)));
typedef unsigned int u32x4  __attribute__((ext_vector_type(4)));
typedef unsigned int u32x2  __attribute__((ext_vector_type(2)));
typedef __bf16       bf16x8 __attribute__((ext_vector_type(8)));

__device__ __forceinline__ float ssp_pre(float acc, float bpre) {
  // ssp(acc + b) with bpre = b*log2e:  ln2 * log2(0.5*2^(acc*log2e + bpre) + 0.5)
  float t = __builtin_amdgcn_exp2f(__builtin_fmaf(acc, 1.44269504089f, bpre));
  return 0.69314718056f * __builtin_amdgcn_logf(__builtin_fmaf(t, 0.5f, 0.5f));
}

__device__ __forceinline__ float ssp_f(float v) {
  float t = __builtin_amdgcn_exp2f(v * 1.44269504089f);
  return 0.69314718056f * __builtin_amdgcn_logf(__builtin_fmaf(t, 0.5f, 0.5f));
}

__device__ __forceinline__ unsigned short f2bfu(float f) {
  __hip_bfloat16 h = __float2bfloat16(f);
  return __builtin_bit_cast(unsigned short, h);
}

__device__ __forceinline__ u32x4 pack8(f32x4 a, f32x4 b) {
  u32x4 u;
  u.x = (unsigned)f2bfu(a.x) | ((unsigned)f2bfu(a.y) << 16);
  u.y = (unsigned)f2bfu(a.z) | ((unsigned)f2bfu(a.w) << 16);
  u.z = (unsigned)f2bfu(b.x) | ((unsigned)f2bfu(b.y) << 16);
  u.w = (unsigned)f2bfu(b.z) | ((unsigned)f2bfu(b.w) << 16);
  return u;
}

__device__ __forceinline__ f32x4 fzero4() { f32x4 z = {0.f, 0.f, 0.f, 0.f}; return z; }

#define SWZ(j) (((j) & 7) << 4)

// ---------------------------------------------------------------------------
// Weight prep: Weff[b] = W + A[b] @ B[b].
// Filter layers (l=1,2,3) stored TRANSPOSED bf16 [b][nout][din] for MFMA A-frags.
// bc/a0/a1 (l=0,4,5) stored fp32 [b][k][n] for the VALU dense kernels.
// ---------------------------------------------------------------------------
__global__ void prep_weights(
    const float* __restrict__ W_bc, const float* __restrict__ A_bc, const float* __restrict__ B_bc,
    const float* __restrict__ W_f0, const float* __restrict__ A_f0, const float* __restrict__ B_f0,
    const float* __restrict__ W_f1, const float* __restrict__ A_f1, const float* __restrict__ B_f1,
    const float* __restrict__ W_f2, const float* __restrict__ A_f2, const float* __restrict__ B_f2,
    const float* __restrict__ W_a0, const float* __restrict__ A_a0, const float* __restrict__ B_a0,
    const float* __restrict__ W_a1, const float* __restrict__ A_a1, const float* __restrict__ B_a1,
    unsigned short* __restrict__ Wt0, unsigned short* __restrict__ Wt1, unsigned short* __restrict__ Wt2,
    float* __restrict__ Wbc, float* __restrict__ Wa0, float* __restrict__ Wa1)
{
  const int l = blockIdx.y, b = blockIdx.z;
  const int e = blockIdx.x * 256 + threadIdx.x;
  const float *W, *A, *Bm; int din;
  switch (l) {
    case 0:  W = W_bc; A = A_bc; Bm = B_bc; din = 128; break;
    case 1:  W = W_f0; A = A_f0; Bm = B_f0; din = 64;  break;
    case 2:  W = W_f1; A = A_f1; Bm = B_f1; din = 128; break;
    case 3:  W = W_f2; A = A_f2; Bm = B_f2; din = 128; break;
    case 4:  W = W_a0; A = A_a0; Bm = B_a0; din = 128; break;
    default: W = W_a1; A = A_a1; Bm = B_a1; din = 128; break;
  }
  if (e >= din * 128) return;
  const int k = e >> 7, n = e & 127;
  float wv = W[k * 128 + n];
  #pragma unroll
  for (int r = 0; r < 4; ++r)
    wv += A[(b * din + k) * 4 + r] * Bm[(b * 4 + r) * 128 + n];
  if (l == 1)      Wt0[(b * 128 + n) * 64  + k] = f2bfu(wv);
  else if (l == 2) Wt1[(b * 128 + n) * 128 + k] = f2bfu(wv);
  else if (l == 3) Wt2[(b * 128 + n) * 128 + k] = f2bfu(wv);
  else if (l == 0) Wbc[(b * 128 + k) * 128 + n] = wv;
  else if (l == 4) Wa0[(b * 128 + k) * 128 + n] = wv;
  else             Wa1[(b * 128 + k) * 128 + n] = wv;
}

// ---------------------------------------------------------------------------
// dense_ssp: out[row,n] = ssp(sum_k in[row,k]*W[b,k,n] + bias[n])
// rows = [2*512], fp32 exact. 4 rows per block, 512 threads (1 output each).
// ---------------------------------------------------------------------------
__global__ __launch_bounds__(512) void dense_ssp(
    const float* __restrict__ in, const float* __restrict__ W,
    const float* __restrict__ bias, float* __restrict__ out)
{
  __shared__ float in_l[4][128];
  const int t = threadIdx.x;
  const int rg0 = blockIdx.x << 2;
  const int b = rg0 >> 9;
  in_l[t >> 7][t & 127] = in[rg0 * 128 + t];
  __syncthreads();
  const int j = t >> 7, n = t & 127;
  const float* wp = W + (b << 14) + n;
  const float* ip = in_l[j];
  float acc = 0.f;
  #pragma unroll 8
  for (int k = 0; k < 128; ++k) acc += ip[k] * wp[k << 7];
  out[(rg0 + j) * 128 + n] = ssp_f(acc + bias[n]);
}

// ---------------------------------------------------------------------------
// dense2_ssp: fused final two atomwise layers.
// h = ssp((in+in2) @ W0 + b0); out = ssp(h @ W1 + b1) + resid
// ---------------------------------------------------------------------------
__global__ __launch_bounds__(512) void dense2_ssp(
    const float* __restrict__ in, const float* __restrict__ in2,
    const float* __restrict__ W0, const float* __restrict__ b0,
    const float* __restrict__ W1, const float* __restrict__ b1,
    const float* __restrict__ resid, float* __restrict__ out)
{
  __shared__ float in_l[4][128];
  __shared__ float h_l[4][128];
  const int t = threadIdx.x;
  const int rg0 = blockIdx.x << 2;
  const int b = rg0 >> 9;
  in_l[t >> 7][t & 127] = in[rg0 * 128 + t] + in2[rg0 * 128 + t];
  __syncthreads();
  const int j = t >> 7, n = t & 127;
  {
    const float* wp = W0 + (b << 14) + n;
    const float* ip = in_l[j];
    float acc = 0.f;
    #pragma unroll 8
    for (int k = 0; k < 128; ++k) acc += ip[k] * wp[k << 7];
    h_l[j][n] = ssp_f(acc + b0[n]);
  }
  __syncthreads();
  {
    const float* wp = W1 + (b << 14) + n;
    const float* ip = h_l[j];
    float acc = 0.f;
    #pragma unroll 8
    for (int k = 0; k < 128; ++k) acc += ip[k] * wp[k << 7];
    const int oi = (rg0 + j) * 128 + n;
    out[oi] = ssp_f(acc + b1[n]) + resid[oi];
  }
}

// ---------------------------------------------------------------------------
// schnet_core: grid 2048 = (b*512+i)*2 + half. 256 threads = 4 waves.
// Wave w owns nout range [w*32, w*32+32); all waves span all j of the tile.
// Per 64-row tile: pack(prefetched f)->fbuf | B1 | issue next prefetch |
//   G1 | E1->hA | B2 | G2(hA) | E2->hB | B3 | G3(hB) | E3: accy += s*xi*h3
// Loop-end hazards are subsumed by next-iteration barriers (see analysis).
// Weights live in VGPRs for the whole kernel (80 regs).
// ---------------------------------------------------------------------------
__global__ __launch_bounds__(256, 3) void schnet_core(
    const float* __restrict__ f_ij, const float* __restrict__ c_ij,
    const int* __restrict__ mask,
    const unsigned short* __restrict__ Wt0, const unsigned short* __restrict__ Wt1,
    const unsigned short* __restrict__ Wt2,
    const float* __restrict__ bias0, const float* __restrict__ bias1,
    const float* __restrict__ bias2,
    const float* __restrict__ xi, float* __restrict__ ypart)
{
  __shared__ __align__(16) unsigned short fbuf[64 * 64];    // [j][k] bf16, swizzled
  __shared__ __align__(16) unsigned short hA[64 * 128];     // h1, swizzled
  __shared__ __align__(16) unsigned short hB[64 * 128];     // h2, swizzled
  __shared__ int   jlist[576];
  __shared__ float slist[576];
  __shared__ float bias_l[384];                             // 3x128, pre-scaled by log2e
  __shared__ int cnt_s[8], base_s[8], nact_s;

  const int tid  = threadIdx.x;
  const int lane = tid & 63;
  const int w    = tid >> 6;
  const int lrow = lane & 15;
  const int lgrp = lane >> 4;
  const int g    = blockIdx.x;
  const int bi   = g >> 1;              // b*512 + i
  const int h    = g & 1;
  const int b    = bi >> 9;

  // ---- bias staging (pre-scaled so bias-add fuses into exp2 fma) ----
  for (int t = tid; t < 384; t += 256) {
    const float* bp = (t < 128) ? bias0 : (t < 256) ? bias1 : bias2;
    bias_l[t] = bp[t & 127] * 1.44269504089f;
  }

  // ---- deterministic mask compaction ----
  const int mb = bi << 9;               // (b*512+i)*512
  const int jA = tid, jB = tid + 256;
  const int   mA = mask[mb + jA]; const float cA = c_ij[mb + jA];
  const int   mB = mask[mb + jB]; const float cB = c_ij[mb + jB];
  unsigned long long balA = __ballot(mA != 0);
  unsigned long long balB = __ballot(mB != 0);
  if (lane == 0) { cnt_s[w] = __popcll(balA); cnt_s[4 + w] = __popcll(balB); }
  __syncthreads();
  if (tid == 0) {
    int s = 0;
    for (int c = 0; c < 8; ++c) { base_s[c] = s; s += cnt_s[c]; }
    nact_s = s;
  }
  __syncthreads();
  const int na = nact_s;
  const unsigned long long lm = (1ull << lane) - 1ull;
  if (mA) { int p = base_s[w]     + __popcll(balA & lm); jlist[p] = jA; slist[p] = cA; }
  if (mB) { int p = base_s[4 + w] + __popcll(balB & lm); jlist[p] = jB; slist[p] = cB; }
  if (tid < 64) { int idx = na + tid; if (idx < 576) { jlist[idx] = 0; slist[idx] = 0.f; } }
  __syncthreads();

  // ---- this half's tile range ----
  const int tiles = (na + 63) >> 6;
  const int tmid  = (tiles + 1) >> 1;
  const int t0 = h ? tmid : 0;
  const int t1 = h ? tiles : tmid;

  const int mg = w;
  const float* fbase = f_ij + ((size_t)mb << 6);

  // ---- weights: load ONCE into VGPRs (per-wave A-fragments) ----
  bf16x8 w0f[2][2], w1f[2][4], w2f[2][4];
  #pragma unroll
  for (int nt = 0; nt < 2; ++nt) {
    const int nout = mg * 32 + nt * 16 + lrow;
    const int nb0 = (b * 128 + nout) * 64  + lgrp * 8;
    const int nb1 = (b * 128 + nout) * 128 + lgrp * 8;
    #pragma unroll
    for (int ks = 0; ks < 2; ++ks)
      w0f[nt][ks] = *(const bf16x8*)(Wt0 + nb0 + ks * 32);
    #pragma unroll
    for (int ks = 0; ks < 4; ++ks) {
      w1f[nt][ks] = *(const bf16x8*)(Wt1 + nb1 + ks * 32);
      w2f[nt][ks] = *(const bf16x8*)(Wt2 + nb1 + ks * 32);
    }
  }

  float accy[2][4] = {{0.f,0.f,0.f,0.f},{0.f,0.f,0.f,0.f}};

  // ---- prefetch first tile into regs ----
  const int r    = tid >> 2;            // staging row 0..63
  const int part = tid & 3;             // 16-float chunk
  f32x4 pre0, pre1, pre2, pre3;
  {
    const int pf = (t0 < t1) ? (t0 << 6) : 0;
    const int ja = jlist[pf + r];
    const f32x4* src = (const f32x4*)(fbase + ja * 64 + part * 16);
    pre0 = src[0]; pre1 = src[1]; pre2 = src[2]; pre3 = src[3];
  }

  for (int tt = t0; tt < t1; ++tt) {
    const int jt0 = tt << 6;
    // ---- S: pack prefetched regs -> fbuf (bf16, swizzled) ----
    {
      char* dst = (char*)fbuf + r * 128;
      const int o0 = (part * 32) ^ SWZ(r);
      *(u32x4*)(dst + o0)        = pack8(pre0, pre1);
      *(u32x4*)(dst + (o0 ^ 16)) = pack8(pre2, pre3);
    }
    __syncthreads();                    // B1: fbuf ready (also: prev-iter hA readers done)

    // ---- issue next tile's gather (lands during this tile's compute) ----
    {
      const int nx = (tt + 1 < t1) ? ((tt + 1) << 6) : jt0;
      const int ja = jlist[nx + r];
      const f32x4* src = (const f32x4*)(fbase + ja * 64 + part * 16);
      pre0 = src[0]; pre1 = src[1]; pre2 = src[2]; pre3 = src[3];
    }

    f32x4 acc[2][4];

    // ---- G1: h1^T = Wt0 * f^T (K=64) ----
    #pragma unroll
    for (int nt = 0; nt < 2; ++nt)
      #pragma unroll
      for (int jt = 0; jt < 4; ++jt) acc[nt][jt] = fzero4();
    #pragma unroll
    for (int jt = 0; jt < 4; ++jt) {
      const int j = jt * 16 + lrow;
      const char* rb = (const char*)fbuf + j * 128;
      const int sw = SWZ(j);
      #pragma unroll
      for (int ks = 0; ks < 2; ++ks) {
        bf16x8 bf = *(const bf16x8*)(rb + ((lgrp * 16 + ks * 64) ^ sw));
        acc[0][jt] = __builtin_amdgcn_mfma_f32_16x16x32_bf16(w0f[0][ks], bf, acc[0][jt], 0, 0, 0);
        acc[1][jt] = __builtin_amdgcn_mfma_f32_16x16x32_bf16(w0f[1][ks], bf, acc[1][jt], 0, 0, 0);
      }
    }
    // ---- E1: ssp -> bf16 -> hA ----
    {
      f32x4 bp0 = *(const f32x4*)(bias_l + mg * 32 + 0  + lgrp * 4);
      f32x4 bp1 = *(const f32x4*)(bias_l + mg * 32 + 16 + lgrp * 4);
      #pragma unroll
      for (int jt = 0; jt < 4; ++jt) {
        const int j = jt * 16 + lrow;
        char* rb = (char*)hA + j * 256;
        const int sw = SWZ(j);
        #pragma unroll
        for (int nt = 0; nt < 2; ++nt) {
          const int n0 = mg * 32 + nt * 16 + lgrp * 4;
          const f32x4 bp = nt ? bp1 : bp0;
          float e0 = ssp_pre(acc[nt][jt].x, bp.x);
          float e1 = ssp_pre(acc[nt][jt].y, bp.y);
          float e2 = ssp_pre(acc[nt][jt].z, bp.z);
          float e3 = ssp_pre(acc[nt][jt].w, bp.w);
          u32x2 pk;
          pk.x = (unsigned)f2bfu(e0) | ((unsigned)f2bfu(e1) << 16);
          pk.y = (unsigned)f2bfu(e2) | ((unsigned)f2bfu(e3) << 16);
          *(u32x2*)(rb + ((n0 * 2) ^ sw)) = pk;
        }
      }
    }
    __syncthreads();                    // B2: hA ready (also: prev-iter hB readers done)

    // ---- G2: h2^T = Wt1 * h1^T (K=128) ----
    #pragma unroll
    for (int nt = 0; nt < 2; ++nt)
      #pragma unroll
      for (int jt = 0; jt < 4; ++jt) acc[nt][jt] = fzero4();
    #pragma unroll
    for (int jt = 0; jt < 4; ++jt) {
      const int j = jt * 16 + lrow;
      const char* rb = (const char*)hA + j * 256;
      const int sw = SWZ(j);
      #pragma unroll
      for (int ks = 0; ks < 4; ++ks) {
        bf16x8 bf = *(const bf16x8*)(rb + ((lgrp * 16 + ks * 64) ^ sw));
        acc[0][jt] = __builtin_amdgcn_mfma_f32_16x16x32_bf16(w1f[0][ks], bf, acc[0][jt], 0, 0, 0);
        acc[1][jt] = __builtin_amdgcn_mfma_f32_16x16x32_bf16(w1f[1][ks], bf, acc[1][jt], 0, 0, 0);
      }
    }
    // ---- E2: ssp -> bf16 -> hB (no barrier needed: hB not read until B3) ----
    {
      f32x4 bp0 = *(const f32x4*)(bias_l + 128 + mg * 32 + 0  + lgrp * 4);
      f32x4 bp1 = *(const f32x4*)(bias_l + 128 + mg * 32 + 16 + lgrp * 4);
      #pragma unroll
      for (int jt = 0; jt < 4; ++jt) {
        const int j = jt * 16 + lrow;
        char* rb = (char*)hB + j * 256;
        const int sw = SWZ(j);
        #pragma unroll
        for (int nt = 0; nt < 2; ++nt) {
          const int n0 = mg * 32 + nt * 16 + lgrp * 4;
          const f32x4 bp = nt ? bp1 : bp0;
          float e0 = ssp_pre(acc[nt][jt].x, bp.x);
          float e1 = ssp_pre(acc[nt][jt].y, bp.y);
          float e2 = ssp_pre(acc[nt][jt].z, bp.z);
          float e3 = ssp_pre(acc[nt][jt].w, bp.w);
          u32x2 pk;
          pk.x = (unsigned)f2bfu(e0) | ((unsigned)f2bfu(e1) << 16);
          pk.y = (unsigned)f2bfu(e2) | ((unsigned)f2bfu(e3) << 16);
          *(u32x2*)(rb + ((n0 * 2) ^ sw)) = pk;
        }
      }
    }
    __syncthreads();                    // B3: hB ready (also: fbuf readers done -> safe for next S)

    // ---- G3: h3^T = Wt2 * h2^T (K=128) ----
    #pragma unroll
    for (int nt = 0; nt < 2; ++nt)
      #pragma unroll
      for (int jt = 0; jt < 4; ++jt) acc[nt][jt] = fzero4();
    #pragma unroll
    for (int jt = 0; jt < 4; ++jt) {
      const int j = jt * 16 + lrow;
      const char* rb = (const char*)hB + j * 256;
      const int sw = SWZ(j);
      #pragma unroll
      for (int ks = 0; ks < 4; ++ks) {
        bf16x8 bf = *(const bf16x8*)(rb + ((lgrp * 16 + ks * 64) ^ sw));
        acc[0][jt] = __builtin_amdgcn_mfma_f32_16x16x32_bf16(w2f[0][ks], bf, acc[0][jt], 0, 0, 0);
        acc[1][jt] = __builtin_amdgcn_mfma_f32_16x16x32_bf16(w2f[1][ks], bf, acc[1][jt], 0, 0, 0);
      }
    }
    // ---- E3: ssp; accy += s_j * xi[j,f] * h3 ----
    {
      f32x4 bp0 = *(const f32x4*)(bias_l + 256 + mg * 32 + 0  + lgrp * 4);
      f32x4 bp1 = *(const f32x4*)(bias_l + 256 + mg * 32 + 16 + lgrp * 4);
      #pragma unroll
      for (int jt = 0; jt < 4; ++jt) {
        const int jj = jt * 16 + lrow;
        const float s  = slist[jt0 + jj];
        const int   ja = jlist[jt0 + jj];
        const float* xr = xi + (((b << 9) + ja) << 7);
        #pragma unroll
        for (int nt = 0; nt < 2; ++nt) {
          const int n0 = mg * 32 + nt * 16 + lgrp * 4;
          const f32x4 bp = nt ? bp1 : bp0;
          f32x4 xv = *(const f32x4*)(xr + n0);
          float h0 = ssp_pre(acc[nt][jt].x, bp.x);
          float h1 = ssp_pre(acc[nt][jt].y, bp.y);
          float h2 = ssp_pre(acc[nt][jt].z, bp.z);
          float h3 = ssp_pre(acc[nt][jt].w, bp.w);
          accy[nt][0] += s * xv.x * h0;
          accy[nt][1] += s * xv.y * h1;
          accy[nt][2] += s * xv.z * h2;
          accy[nt][3] += s * xv.w * h3;
        }
      }
    }
    // no loop-end barrier: next iter's B1/B2 subsume the fbuf/hA/hB hazards
  }

  // ---- reduce over the 16 j-sub-lanes; write partial y ----
  #pragma unroll
  for (int d = 1; d < 16; d <<= 1)
    #pragma unroll
    for (int nt = 0; nt < 2; ++nt)
      #pragma unroll
      for (int rr = 0; rr < 4; ++rr)
        accy[nt][rr] += __shfl_xor(accy[nt][rr], d, 64);
  if (lrow == 0) {
    float* yo = ypart + ((size_t)h << 17) + ((size_t)bi << 7);
    #pragma unroll
    for (int nt = 0; nt < 2; ++nt) {
      const int n0 = mg * 32 + nt * 16 + lgrp * 4;
      f32x4 v = {accy[nt][0], accy[nt][1], accy[nt][2], accy[nt][3]};
      *(f32x4*)(yo + n0) = v;
    }
  }
}

// ---------------------------------------------------------------------------
extern "C" void kernel_launch(void* const* d_in, const int* in_sizes, int n_in,
                              void* d_out, int out_size, void* d_ws, size_t ws_size,
                              hipStream_t stream)
{
  const float* x    = (const float*)d_in[0];
  const float* f_ij = (const float*)d_in[1];
  const float* c_ij = (const float*)d_in[2];
  const int*   mask = (const int*)d_in[3];
  const float* W_bc = (const float*)d_in[4];
  const float* b_bc = (const float*)d_in[5];
  const float* A_bc = (const float*)d_in[6];
  const float* B_bc = (const float*)d_in[7];
  const float* W_f0 = (const float*)d_in[8];
  const float* b_f0 = (const float*)d_in[9];
  const float* A_f0 = (const float*)d_in[10];
  const float* B_f0 = (const float*)d_in[11];
  const float* W_f1 = (const float*)d_in[12];
  const float* b_f1 = (const float*)d_in[13];
  const float* A_f1 = (const float*)d_in[14];
  const float* B_f1 = (const float*)d_in[15];
  const float* W_f2 = (const float*)d_in[16];
  const float* b_f2 = (const float*)d_in[17];
  const float* A_f2 = (const float*)d_in[18];
  const float* B_f2 = (const float*)d_in[19];
  const float* W_a0 = (const float*)d_in[20];
  const float* b_a0 = (const float*)d_in[21];
  const float* A_a0 = (const float*)d_in[22];
  const float* B_a0 = (const float*)d_in[23];
  const float* W_a1 = (const float*)d_in[24];
  const float* b_a1 = (const float*)d_in[25];
  const float* A_a1 = (const float*)d_in[26];
  const float* B_a1 = (const float*)d_in[27];
  float* out = (float*)d_out;

  char* ws = (char*)d_ws;
  unsigned short* Wt0 = (unsigned short*)(ws);            //  32768 B
  unsigned short* Wt1 = (unsigned short*)(ws + 32768);    //  65536 B
  unsigned short* Wt2 = (unsigned short*)(ws + 98304);    //  65536 B
  float* Wbc = (float*)(ws + 163840);                     // 131072 B
  float* Wa0 = (float*)(ws + 294912);                     // 131072 B
  float* Wa1 = (float*)(ws + 425984);                     // 131072 B
  float* xi  = (float*)(ws + 557056);                     // 524288 B
  float* yp  = (float*)(ws + 1081344);                    // 2 x 524288 B (~2.1 MB total)

  prep_weights<<<dim3(64, 6, 2), 256, 0, stream>>>(
      W_bc, A_bc, B_bc, W_f0, A_f0, B_f0, W_f1, A_f1, B_f1,
      W_f2, A_f2, B_f2, W_a0, A_a0, B_a0, W_a1, A_a1, B_a1,
      Wt0, Wt1, Wt2, Wbc, Wa0, Wa1);

  dense_ssp<<<256, 512, 0, stream>>>(x, Wbc, b_bc, xi);

  schnet_core<<<2048, 256, 0, stream>>>(f_ij, c_ij, mask, Wt0, Wt1, Wt2,
                                        b_f0, b_f1, b_f2, xi, yp);

  dense2_ssp<<<256, 512, 0, stream>>>(yp, yp + (1 << 17), Wa0, b_a0,
                                      Wa1, b_a1, x, out);
}

// Round 5
// 112.855 us; speedup vs baseline: 1.0637x; 1.0637x over previous
//
#include <hip/hip_runtime.h>
#include <hip/hip_bf16.h>

// LoRAModulatedSchnetInteraction: B=2, A=512, F=128, Rbf=64, R=4
// Strategy:
//  - Fold LoRA into per-batch effective weights: Weff[b] = W + A[b]@B[b]  (prep_weights)
//  - x_i: exact fp32 VALU dense (dense_ssp); final two atomwise layers fused (dense2_ssp)
//  - Core: per-(b,i,half) block: compact this half's active j (mask), 3-layer bf16-MFMA
//    MLP on f_ij rows, * c_ij * x_i[j,:], masked sum over j -> partial y  (schnet_core)
//  - R5: register-budgeted stall surgery (R4 spilled: 54MB scratch writes).
//    * per-half compaction (halved startup)
//    * staged weight prefetch: only next GEMM's frags in flight (<=32 regs),
//      issued post-previous-GEMM so L2 latency hides under ssp epilogue
//    * guarded f-tile reg prefetch (no last-iter waste)
//    * single hbuf, 4 barriers/tile, LDS ~28.7KB

typedef float        f32x4  __attribute__((ext_vector_type(4)));
typedef unsigned int u32x4  __attribute__((ext_vector_type(4)));
typedef unsigned int u32x2  __attribute__((ext_vector_type(2)));
typedef __bf16       bf16x8 __attribute__((ext_vector_type(8)));

__device__ __forceinline__ float ssp_pre(float acc, float bpre) {
  // ssp(acc + b) with bpre = b*log2e:  ln2 * log2(0.5*2^(acc*log2e + bpre) + 0.5)
  float t = __builtin_amdgcn_exp2f(__builtin_fmaf(acc, 1.44269504089f, bpre));
  return 0.69314718056f * __builtin_amdgcn_logf(__builtin_fmaf(t, 0.5f, 0.5f));
}

__device__ __forceinline__ float ssp_f(float v) {
  float t = __builtin_amdgcn_exp2f(v * 1.44269504089f);
  return 0.69314718056f * __builtin_amdgcn_logf(__builtin_fmaf(t, 0.5f, 0.5f));
}

__device__ __forceinline__ unsigned short f2bfu(float f) {
  __hip_bfloat16 h = __float2bfloat16(f);
  return __builtin_bit_cast(unsigned short, h);
}

__device__ __forceinline__ u32x4 pack8(f32x4 a, f32x4 b) {
  u32x4 u;
  u.x = (unsigned)f2bfu(a.x) | ((unsigned)f2bfu(a.y) << 16);
  u.y = (unsigned)f2bfu(a.z) | ((unsigned)f2bfu(a.w) << 16);
  u.z = (unsigned)f2bfu(b.x) | ((unsigned)f2bfu(b.y) << 16);
  u.w = (unsigned)f2bfu(b.z) | ((unsigned)f2bfu(b.w) << 16);
  return u;
}

__device__ __forceinline__ f32x4 fzero4() { f32x4 z = {0.f, 0.f, 0.f, 0.f}; return z; }

#define SWZ(j) (((j) & 7) << 4)

// ---------------------------------------------------------------------------
// Weight prep: Weff[b] = W + A[b] @ B[b].
// Filter layers (l=1,2,3) stored TRANSPOSED bf16 [b][nout][din] for MFMA A-frags.
// bc/a0/a1 (l=0,4,5) stored fp32 [b][k][n] for the VALU dense kernels.
// ---------------------------------------------------------------------------
__global__ void prep_weights(
    const float* __restrict__ W_bc, const float* __restrict__ A_bc, const float* __restrict__ B_bc,
    const float* __restrict__ W_f0, const float* __restrict__ A_f0, const float* __restrict__ B_f0,
    const float* __restrict__ W_f1, const float* __restrict__ A_f1, const float* __restrict__ B_f1,
    const float* __restrict__ W_f2, const float* __restrict__ A_f2, const float* __restrict__ B_f2,
    const float* __restrict__ W_a0, const float* __restrict__ A_a0, const float* __restrict__ B_a0,
    const float* __restrict__ W_a1, const float* __restrict__ A_a1, const float* __restrict__ B_a1,
    unsigned short* __restrict__ Wt0, unsigned short* __restrict__ Wt1, unsigned short* __restrict__ Wt2,
    float* __restrict__ Wbc, float* __restrict__ Wa0, float* __restrict__ Wa1)
{
  const int l = blockIdx.y, b = blockIdx.z;
  const int e = blockIdx.x * 256 + threadIdx.x;
  const float *W, *A, *Bm; int din;
  switch (l) {
    case 0:  W = W_bc; A = A_bc; Bm = B_bc; din = 128; break;
    case 1:  W = W_f0; A = A_f0; Bm = B_f0; din = 64;  break;
    case 2:  W = W_f1; A = A_f1; Bm = B_f1; din = 128; break;
    case 3:  W = W_f2; A = A_f2; Bm = B_f2; din = 128; break;
    case 4:  W = W_a0; A = A_a0; Bm = B_a0; din = 128; break;
    default: W = W_a1; A = A_a1; Bm = B_a1; din = 128; break;
  }
  if (e >= din * 128) return;
  const int k = e >> 7, n = e & 127;
  float wv = W[k * 128 + n];
  #pragma unroll
  for (int r = 0; r < 4; ++r)
    wv += A[(b * din + k) * 4 + r] * Bm[(b * 4 + r) * 128 + n];
  if (l == 1)      Wt0[(b * 128 + n) * 64  + k] = f2bfu(wv);
  else if (l == 2) Wt1[(b * 128 + n) * 128 + k] = f2bfu(wv);
  else if (l == 3) Wt2[(b * 128 + n) * 128 + k] = f2bfu(wv);
  else if (l == 0) Wbc[(b * 128 + k) * 128 + n] = wv;
  else if (l == 4) Wa0[(b * 128 + k) * 128 + n] = wv;
  else             Wa1[(b * 128 + k) * 128 + n] = wv;
}

// ---------------------------------------------------------------------------
// dense_ssp: out[row,n] = ssp(sum_k in[row,k]*W[b,k,n] + bias[n])
// ---------------------------------------------------------------------------
__global__ __launch_bounds__(512) void dense_ssp(
    const float* __restrict__ in, const float* __restrict__ W,
    const float* __restrict__ bias, float* __restrict__ out)
{
  __shared__ float in_l[4][128];
  const int t = threadIdx.x;
  const int rg0 = blockIdx.x << 2;
  const int b = rg0 >> 9;
  in_l[t >> 7][t & 127] = in[rg0 * 128 + t];
  __syncthreads();
  const int j = t >> 7, n = t & 127;
  const float* wp = W + (b << 14) + n;
  const float* ip = in_l[j];
  float acc = 0.f;
  #pragma unroll 8
  for (int k = 0; k < 128; ++k) acc += ip[k] * wp[k << 7];
  out[(rg0 + j) * 128 + n] = ssp_f(acc + bias[n]);
}

// ---------------------------------------------------------------------------
// dense2_ssp: fused final two atomwise layers.
// h = ssp((in+in2) @ W0 + b0); out = ssp(h @ W1 + b1) + resid
// ---------------------------------------------------------------------------
__global__ __launch_bounds__(512) void dense2_ssp(
    const float* __restrict__ in, const float* __restrict__ in2,
    const float* __restrict__ W0, const float* __restrict__ b0,
    const float* __restrict__ W1, const float* __restrict__ b1,
    const float* __restrict__ resid, float* __restrict__ out)
{
  __shared__ float in_l[4][128];
  __shared__ float h_l[4][128];
  const int t = threadIdx.x;
  const int rg0 = blockIdx.x << 2;
  const int b = rg0 >> 9;
  in_l[t >> 7][t & 127] = in[rg0 * 128 + t] + in2[rg0 * 128 + t];
  __syncthreads();
  const int j = t >> 7, n = t & 127;
  {
    const float* wp = W0 + (b << 14) + n;
    const float* ip = in_l[j];
    float acc = 0.f;
    #pragma unroll 8
    for (int k = 0; k < 128; ++k) acc += ip[k] * wp[k << 7];
    h_l[j][n] = ssp_f(acc + b0[n]);
  }
  __syncthreads();
  {
    const float* wp = W1 + (b << 14) + n;
    const float* ip = h_l[j];
    float acc = 0.f;
    #pragma unroll 8
    for (int k = 0; k < 128; ++k) acc += ip[k] * wp[k << 7];
    const int oi = (rg0 + j) * 128 + n;
    out[oi] = ssp_f(acc + b1[n]) + resid[oi];
  }
}

// ---------------------------------------------------------------------------
// schnet_core: grid 2048 = (b*512+i)*2 + half. 256 threads = 4 waves.
// Block owns j in [h*256, (h+1)*256); compacts its own 256-entry mask slice.
// Wave w owns nout range [w*32, w*32+32); all waves span all j of the tile.
// Per 64-row tile:
//   S: pack prefetched f -> fbuf | B1 | guarded next-f prefetch issue |
//   G1(wfA) | issue wfB | E1->h | B2 | G2(wfB) | B2' | issue wfC | E2->h |
//   B3 | G3(wfC) | issue wfA' | E3: accy += s*xi*h3
// Hazards at loop edges: fbuf written at S(t), last read G1(t-1) which all
// waves finished before B2(t-1) (2 barriers earlier) -> safe. h written at
// E1(t) after B1(t); last readers G3(t-1) finish before any wave passes
// B1(t) -> safe. 4 barriers/tile total.
// Weight frags: only the NEXT GEMM's set in flight (<=32 VGPR), issued after
// the previous GEMM so ~300cy L2 latency hides under the ssp epilogue.
// ---------------------------------------------------------------------------
__global__ __launch_bounds__(256, 4) void schnet_core(
    const float* __restrict__ f_ij, const float* __restrict__ c_ij,
    const int* __restrict__ mask,
    const unsigned short* __restrict__ Wt0, const unsigned short* __restrict__ Wt1,
    const unsigned short* __restrict__ Wt2,
    const float* __restrict__ bias0, const float* __restrict__ bias1,
    const float* __restrict__ bias2,
    const float* __restrict__ xi, float* __restrict__ ypart)
{
  __shared__ __align__(16) unsigned short fbuf[64 * 64];    // [j][k] bf16, swizzled
  __shared__ __align__(16) unsigned short hbuf[64 * 128];   // h, swizzled
  __shared__ int   jlist[320];
  __shared__ float slist[320];
  __shared__ float bias_l[384];                             // 3x128, pre-scaled by log2e
  __shared__ int cnt_s[4], base_s[4], nact_s;

  const int tid  = threadIdx.x;
  const int lane = tid & 63;
  const int w    = tid >> 6;
  const int lrow = lane & 15;
  const int lgrp = lane >> 4;
  const int g    = blockIdx.x;
  const int bi   = g >> 1;              // b*512 + i
  const int h    = g & 1;
  const int b    = bi >> 9;

  // ---- bias staging (pre-scaled so bias-add fuses into exp2 fma) ----
  for (int t = tid; t < 384; t += 256) {
    const float* bp = (t < 128) ? bias0 : (t < 256) ? bias1 : bias2;
    bias_l[t] = bp[t & 127] * 1.44269504089f;
  }

  // ---- deterministic compaction of this half's 256 j's ----
  const int mb = bi << 9;               // (b*512+i)*512
  const int jg = (h << 8) + tid;        // global j
  const int   mA = mask[mb + jg];
  const float cA = c_ij[mb + jg];
  unsigned long long bal = __ballot(mA != 0);
  if (lane == 0) cnt_s[w] = __popcll(bal);
  __syncthreads();
  if (tid == 0) {
    int s = 0;
    for (int c = 0; c < 4; ++c) { base_s[c] = s; s += cnt_s[c]; }
    nact_s = s;
  }
  __syncthreads();
  const int na = nact_s;
  const unsigned long long lm = (1ull << lane) - 1ull;
  if (mA) { int p = base_s[w] + __popcll(bal & lm); jlist[p] = jg; slist[p] = cA; }
  if (tid < 64) { int idx = na + tid; if (idx < 320) { jlist[idx] = 0; slist[idx] = 0.f; } }
  __syncthreads();

  const int tiles = (na + 63) >> 6;     // 0..4 (na <= 256)

  const int mg = w;
  const float* fbase = f_ij + ((size_t)mb << 6);

  // per-wave A-frag base offsets
  const int wbase0 = ((b << 7) + mg * 32 + lrow) * 64  + (lgrp << 3);
  const int wbase1 = ((b << 7) + mg * 32 + lrow) * 128 + (lgrp << 3);

  float accy[2][4] = {{0.f,0.f,0.f,0.f},{0.f,0.f,0.f,0.f}};

  // ---- initial wfA (G1 weights, 16 regs) ----
  bf16x8 wfA[2][2];
  {
    const unsigned short* wp = Wt0 + wbase0;
    #pragma unroll
    for (int nt = 0; nt < 2; ++nt)
      #pragma unroll
      for (int ks = 0; ks < 2; ++ks)
        wfA[nt][ks] = *(const bf16x8*)(wp + nt * (16 * 64) + ks * 32);
  }

  // ---- prefetch first f tile into regs ----
  const int r    = tid >> 2;            // staging row 0..63
  const int part = tid & 3;             // 16-float chunk
  f32x4 pre0, pre1, pre2, pre3;
  {
    const int ja = jlist[r];            // jlist[0..63] valid even if na==0
    const f32x4* src = (const f32x4*)(fbase + ja * 64 + part * 16);
    pre0 = src[0]; pre1 = src[1]; pre2 = src[2]; pre3 = src[3];
  }

  for (int tt = 0; tt < tiles; ++tt) {
    const int jt0 = tt << 6;
    // ---- S: pack prefetched regs -> fbuf (bf16, swizzled) ----
    {
      char* dst = (char*)fbuf + r * 128;
      const int o0 = (part * 32) ^ SWZ(r);
      *(u32x4*)(dst + o0)        = pack8(pre0, pre1);
      *(u32x4*)(dst + (o0 ^ 16)) = pack8(pre2, pre3);
    }
    __syncthreads();                    // B1: fbuf ready

    // ---- guarded next-f prefetch (uniform branch) ----
    if (tt + 1 < tiles) {
      const int ja = jlist[((tt + 1) << 6) + r];
      const f32x4* src = (const f32x4*)(fbase + ja * 64 + part * 16);
      pre0 = src[0]; pre1 = src[1]; pre2 = src[2]; pre3 = src[3];
    }

    f32x4 acc[2][4];

    // ---- G1: h1^T = Wt0 * f^T (K=64) ----
    #pragma unroll
    for (int nt = 0; nt < 2; ++nt)
      #pragma unroll
      for (int jt = 0; jt < 4; ++jt) acc[nt][jt] = fzero4();
    #pragma unroll
    for (int jt = 0; jt < 4; ++jt) {
      const int j = jt * 16 + lrow;
      const char* rb = (const char*)fbuf + j * 128;
      const int sw = SWZ(j);
      #pragma unroll
      for (int ks = 0; ks < 2; ++ks) {
        bf16x8 bf = *(const bf16x8*)(rb + ((lgrp * 16 + ks * 64) ^ sw));
        acc[0][jt] = __builtin_amdgcn_mfma_f32_16x16x32_bf16(wfA[0][ks], bf, acc[0][jt], 0, 0, 0);
        acc[1][jt] = __builtin_amdgcn_mfma_f32_16x16x32_bf16(wfA[1][ks], bf, acc[1][jt], 0, 0, 0);
      }
    }

    // ---- issue wfB (G2 weights): in flight during E1 (~700cy >> L2 300cy) ----
    bf16x8 wfB[2][4];
    {
      const unsigned short* wp = Wt1 + wbase1;
      asm volatile("" : "+v"(wp));      // anti-LICM: reload per tile
      #pragma unroll
      for (int nt = 0; nt < 2; ++nt)
        #pragma unroll
        for (int ks = 0; ks < 4; ++ks)
          wfB[nt][ks] = *(const bf16x8*)(wp + nt * (16 * 128) + ks * 32);
    }

    // ---- E1: ssp -> bf16 -> hbuf ----
    {
      f32x4 bp0 = *(const f32x4*)(bias_l + mg * 32 + 0  + lgrp * 4);
      f32x4 bp1 = *(const f32x4*)(bias_l + mg * 32 + 16 + lgrp * 4);
      #pragma unroll
      for (int jt = 0; jt < 4; ++jt) {
        const int j = jt * 16 + lrow;
        char* rb = (char*)hbuf + j * 256;
        const int sw = SWZ(j);
        #pragma unroll
        for (int nt = 0; nt < 2; ++nt) {
          const int n0 = mg * 32 + nt * 16 + lgrp * 4;
          const f32x4 bp = nt ? bp1 : bp0;
          float e0 = ssp_pre(acc[nt][jt].x, bp.x);
          float e1 = ssp_pre(acc[nt][jt].y, bp.y);
          float e2 = ssp_pre(acc[nt][jt].z, bp.z);
          float e3 = ssp_pre(acc[nt][jt].w, bp.w);
          u32x2 pk;
          pk.x = (unsigned)f2bfu(e0) | ((unsigned)f2bfu(e1) << 16);
          pk.y = (unsigned)f2bfu(e2) | ((unsigned)f2bfu(e3) << 16);
          *(u32x2*)(rb + ((n0 * 2) ^ sw)) = pk;
        }
      }
    }
    __syncthreads();                    // B2: h1 ready

    // ---- G2: h2^T = Wt1 * h1^T (K=128) ----
    #pragma unroll
    for (int nt = 0; nt < 2; ++nt)
      #pragma unroll
      for (int jt = 0; jt < 4; ++jt) acc[nt][jt] = fzero4();
    #pragma unroll
    for (int jt = 0; jt < 4; ++jt) {
      const int j = jt * 16 + lrow;
      const char* rb = (const char*)hbuf + j * 256;
      const int sw = SWZ(j);
      #pragma unroll
      for (int ks = 0; ks < 4; ++ks) {
        bf16x8 bf = *(const bf16x8*)(rb + ((lgrp * 16 + ks * 64) ^ sw));
        acc[0][jt] = __builtin_amdgcn_mfma_f32_16x16x32_bf16(wfB[0][ks], bf, acc[0][jt], 0, 0, 0);
        acc[1][jt] = __builtin_amdgcn_mfma_f32_16x16x32_bf16(wfB[1][ks], bf, acc[1][jt], 0, 0, 0);
      }
    }
    __syncthreads();                    // B2': h1 readers done (h overwrite safe)

    // ---- issue wfC (G3 weights): in flight during E2 ----
    bf16x8 wfC[2][4];
    {
      const unsigned short* wp = Wt2 + wbase1;
      asm volatile("" : "+v"(wp));
      #pragma unroll
      for (int nt = 0; nt < 2; ++nt)
        #pragma unroll
        for (int ks = 0; ks < 4; ++ks)
          wfC[nt][ks] = *(const bf16x8*)(wp + nt * (16 * 128) + ks * 32);
    }

    // ---- E2: ssp -> bf16 -> hbuf ----
    {
      f32x4 bp0 = *(const f32x4*)(bias_l + 128 + mg * 32 + 0  + lgrp * 4);
      f32x4 bp1 = *(const f32x4*)(bias_l + 128 + mg * 32 + 16 + lgrp * 4);
      #pragma unroll
      for (int jt = 0; jt < 4; ++jt) {
        const int j = jt * 16 + lrow;
        char* rb = (char*)hbuf + j * 256;
        const int sw = SWZ(j);
        #pragma unroll
        for (int nt = 0; nt < 2; ++nt) {
          const int n0 = mg * 32 + nt * 16 + lgrp * 4;
          const f32x4 bp = nt ? bp1 : bp0;
          float e0 = ssp_pre(acc[nt][jt].x, bp.x);
          float e1 = ssp_pre(acc[nt][jt].y, bp.y);
          float e2 = ssp_pre(acc[nt][jt].z, bp.z);
          float e3 = ssp_pre(acc[nt][jt].w, bp.w);
          u32x2 pk;
          pk.x = (unsigned)f2bfu(e0) | ((unsigned)f2bfu(e1) << 16);
          pk.y = (unsigned)f2bfu(e2) | ((unsigned)f2bfu(e3) << 16);
          *(u32x2*)(rb + ((n0 * 2) ^ sw)) = pk;
        }
      }
    }
    __syncthreads();                    // B3: h2 ready

    // ---- G3: h3^T = Wt2 * h2^T (K=128) ----
    #pragma unroll
    for (int nt = 0; nt < 2; ++nt)
      #pragma unroll
      for (int jt = 0; jt < 4; ++jt) acc[nt][jt] = fzero4();
    #pragma unroll
    for (int jt = 0; jt < 4; ++jt) {
      const int j = jt * 16 + lrow;
      const char* rb = (const char*)hbuf + j * 256;
      const int sw = SWZ(j);
      #pragma unroll
      for (int ks = 0; ks < 4; ++ks) {
        bf16x8 bf = *(const bf16x8*)(rb + ((lgrp * 16 + ks * 64) ^ sw));
        acc[0][jt] = __builtin_amdgcn_mfma_f32_16x16x32_bf16(wfC[0][ks], bf, acc[0][jt], 0, 0, 0);
        acc[1][jt] = __builtin_amdgcn_mfma_f32_16x16x32_bf16(wfC[1][ks], bf, acc[1][jt], 0, 0, 0);
      }
    }

    // ---- issue wfA' (next tile's G1 weights): in flight during E3 ----
    {
      const unsigned short* wp = Wt0 + wbase0;
      asm volatile("" : "+v"(wp));
      #pragma unroll
      for (int nt = 0; nt < 2; ++nt)
        #pragma unroll
        for (int ks = 0; ks < 2; ++ks)
          wfA[nt][ks] = *(const bf16x8*)(wp + nt * (16 * 64) + ks * 32);
    }

    // ---- E3: ssp; accy += s_j * xi[j,f] * h3 ----
    {
      f32x4 bp0 = *(const f32x4*)(bias_l + 256 + mg * 32 + 0  + lgrp * 4);
      f32x4 bp1 = *(const f32x4*)(bias_l + 256 + mg * 32 + 16 + lgrp * 4);
      #pragma unroll
      for (int jt = 0; jt < 4; ++jt) {
        const int jj = jt * 16 + lrow;
        const float s  = slist[jt0 + jj];
        const int   ja = jlist[jt0 + jj];
        const float* xr = xi + (((b << 9) + ja) << 7);
        #pragma unroll
        for (int nt = 0; nt < 2; ++nt) {
          const int n0 = mg * 32 + nt * 16 + lgrp * 4;
          const f32x4 bp = nt ? bp1 : bp0;
          f32x4 xv = *(const f32x4*)(xr + n0);
          float h0 = ssp_pre(acc[nt][jt].x, bp.x);
          float h1 = ssp_pre(acc[nt][jt].y, bp.y);
          float h2 = ssp_pre(acc[nt][jt].z, bp.z);
          float h3 = ssp_pre(acc[nt][jt].w, bp.w);
          accy[nt][0] += s * xv.x * h0;
          accy[nt][1] += s * xv.y * h1;
          accy[nt][2] += s * xv.z * h2;
          accy[nt][3] += s * xv.w * h3;
        }
      }
    }
    // no loop-end barrier: B1(t+1) orders G3/E3 reads vs next writes (see header)
  }

  // ---- reduce over the 16 j-sub-lanes; write partial y ----
  #pragma unroll
  for (int d = 1; d < 16; d <<= 1)
    #pragma unroll
    for (int nt = 0; nt < 2; ++nt)
      #pragma unroll
      for (int rr = 0; rr < 4; ++rr)
        accy[nt][rr] += __shfl_xor(accy[nt][rr], d, 64);
  if (lrow == 0) {
    float* yo = ypart + ((size_t)h << 17) + ((size_t)bi << 7);
    #pragma unroll
    for (int nt = 0; nt < 2; ++nt) {
      const int n0 = mg * 32 + nt * 16 + lgrp * 4;
      f32x4 v = {accy[nt][0], accy[nt][1], accy[nt][2], accy[nt][3]};
      *(f32x4*)(yo + n0) = v;
    }
  }
}

// ---------------------------------------------------------------------------
extern "C" void kernel_launch(void* const* d_in, const int* in_sizes, int n_in,
                              void* d_out, int out_size, void* d_ws, size_t ws_size,
                              hipStream_t stream)
{
  const float* x    = (const float*)d_in[0];
  const float* f_ij = (const float*)d_in[1];
  const float* c_ij = (const float*)d_in[2];
  const int*   mask = (const int*)d_in[3];
  const float* W_bc = (const float*)d_in[4];
  const float* b_bc = (const float*)d_in[5];
  const float* A_bc = (const float*)d_in[6];
  const float* B_bc = (const float*)d_in[7];
  const float* W_f0 = (const float*)d_in[8];
  const float* b_f0 = (const float*)d_in[9];
  const float* A_f0 = (const float*)d_in[10];
  const float* B_f0 = (const float*)d_in[11];
  const float* W_f1 = (const float*)d_in[12];
  const float* b_f1 = (const float*)d_in[13];
  const float* A_f1 = (const float*)d_in[14];
  const float* B_f1 = (const float*)d_in[15];
  const float* W_f2 = (const float*)d_in[16];
  const float* b_f2 = (const float*)d_in[17];
  const float* A_f2 = (const float*)d_in[18];
  const float* B_f2 = (const float*)d_in[19];
  const float* W_a0 = (const float*)d_in[20];
  const float* b_a0 = (const float*)d_in[21];
  const float* A_a0 = (const float*)d_in[22];
  const float* B_a0 = (const float*)d_in[23];
  const float* W_a1 = (const float*)d_in[24];
  const float* b_a1 = (const float*)d_in[25];
  const float* A_a1 = (const float*)d_in[26];
  const float* B_a1 = (const float*)d_in[27];
  float* out = (float*)d_out;

  char* ws = (char*)d_ws;
  unsigned short* Wt0 = (unsigned short*)(ws);            //  32768 B
  unsigned short* Wt1 = (unsigned short*)(ws + 32768);    //  65536 B
  unsigned short* Wt2 = (unsigned short*)(ws + 98304);    //  65536 B
  float* Wbc = (float*)(ws + 163840);                     // 131072 B
  float* Wa0 = (float*)(ws + 294912);                     // 131072 B
  float* Wa1 = (float*)(ws + 425984);                     // 131072 B
  float* xi  = (float*)(ws + 557056);                     // 524288 B
  float* yp  = (float*)(ws + 1081344);                    // 2 x 524288 B (~2.1 MB total)

  prep_weights<<<dim3(64, 6, 2), 256, 0, stream>>>(
      W_bc, A_bc, B_bc, W_f0, A_f0, B_f0, W_f1, A_f1, B_f1,
      W_f2, A_f2, B_f2, W_a0, A_a0, B_a0, W_a1, A_a1, B_a1,
      Wt0, Wt1, Wt2, Wbc, Wa0, Wa1);

  dense_ssp<<<256, 512, 0, stream>>>(x, Wbc, b_bc, xi);

  schnet_core<<<2048, 256, 0, stream>>>(f_ij, c_ij, mask, Wt0, Wt1, Wt2,
                                        b_f0, b_f1, b_f2, xi, yp);

  dense2_ssp<<<256, 512, 0, stream>>>(yp, yp + (1 << 17), Wa0, b_a0,
                                      Wa1, b_a1, x, out);
}

// Round 6
// 97.092 us; speedup vs baseline: 1.2363x; 1.1623x over previous
//
#include <hip/hip_runtime.h>
#include <hip/hip_bf16.h>

// LoRAModulatedSchnetInteraction: B=2, A=512, F=128, Rbf=64, R=4
// Strategy:
//  - Fold LoRA into per-batch effective weights: Weff[b] = W + A[b]@B[b]  (prep_weights)
//  - x_i: exact fp32 VALU dense (dense_ssp); final two atomwise layers fused (dense2_ssp)
//  - Core: per-(b,i) block: compact active j (mask), 3-layer bf16-MFMA MLP on f_ij rows,
//    * c_ij * x_i[j,:], masked sum over j -> y  (schnet_core)
//  - R6: uniform one-generation grid (1024 blocks = 4/CU resident, zero tail);
//    16-row sub-tile pruning (uniform guards, static unroll); ssp algebra folded
//    (ln2 into Wt1/Wt2/slist, 0.5 into bias) -> fma+exp2+add+log2 per elem;
//    hbuf 16-slot swizzle (4-way instead of 8-way conflicts).

typedef float        f32x4  __attribute__((ext_vector_type(4)));
typedef unsigned int u32x4  __attribute__((ext_vector_type(4)));
typedef unsigned int u32x2  __attribute__((ext_vector_type(2)));
typedef __bf16       bf16x8 __attribute__((ext_vector_type(8)));

#define LOG2E 1.44269504089f
#define LN2   0.69314718056f

// h' = ssp(acc+b)/ln2 = log2(2^(acc*log2e + b*log2e - 1) + 0.5)
// bpre = b*log2e - 1. Consumers absorb the ln2 (next-layer weights / slist).
__device__ __forceinline__ float ssp_pre(float acc, float bpre) {
  float t = __builtin_amdgcn_exp2f(__builtin_fmaf(acc, LOG2E, bpre));
  return __builtin_amdgcn_logf(t + 0.5f);
}

__device__ __forceinline__ float ssp_f(float v) {
  float t = __builtin_amdgcn_exp2f(v * LOG2E);
  return LN2 * __builtin_amdgcn_logf(__builtin_fmaf(t, 0.5f, 0.5f));
}

__device__ __forceinline__ unsigned short f2bfu(float f) {
  __hip_bfloat16 h = __float2bfloat16(f);
  return __builtin_bit_cast(unsigned short, h);
}

__device__ __forceinline__ u32x4 pack8(f32x4 a, f32x4 b) {
  u32x4 u;
  u.x = (unsigned)f2bfu(a.x) | ((unsigned)f2bfu(a.y) << 16);
  u.y = (unsigned)f2bfu(a.z) | ((unsigned)f2bfu(a.w) << 16);
  u.z = (unsigned)f2bfu(b.x) | ((unsigned)f2bfu(b.y) << 16);
  u.w = (unsigned)f2bfu(b.z) | ((unsigned)f2bfu(b.w) << 16);
  return u;
}

__device__ __forceinline__ f32x4 fzero4() { f32x4 z = {0.f, 0.f, 0.f, 0.f}; return z; }

#define SWZF(j) (((j) & 7) << 4)     // fbuf: 128B rows, 8 slots
#define SWZH(j) (((j) & 15) << 4)    // hbuf: 256B rows, 16 slots

// ---------------------------------------------------------------------------
// Weight prep: Weff[b] = W + A[b] @ B[b].
// Filter layers (l=1,2,3) stored TRANSPOSED bf16 [b][nout][din]; l=2,3 pre-scaled
// by ln2 (ssp log2-form folding). bc/a0/a1 stored fp32 [b][k][n].
// ---------------------------------------------------------------------------
__global__ void prep_weights(
    const float* __restrict__ W_bc, const float* __restrict__ A_bc, const float* __restrict__ B_bc,
    const float* __restrict__ W_f0, const float* __restrict__ A_f0, const float* __restrict__ B_f0,
    const float* __restrict__ W_f1, const float* __restrict__ A_f1, const float* __restrict__ B_f1,
    const float* __restrict__ W_f2, const float* __restrict__ A_f2, const float* __restrict__ B_f2,
    const float* __restrict__ W_a0, const float* __restrict__ A_a0, const float* __restrict__ B_a0,
    const float* __restrict__ W_a1, const float* __restrict__ A_a1, const float* __restrict__ B_a1,
    unsigned short* __restrict__ Wt0, unsigned short* __restrict__ Wt1, unsigned short* __restrict__ Wt2,
    float* __restrict__ Wbc, float* __restrict__ Wa0, float* __restrict__ Wa1)
{
  const int l = blockIdx.y, b = blockIdx.z;
  const int e = blockIdx.x * 256 + threadIdx.x;
  const float *W, *A, *Bm; int din;
  switch (l) {
    case 0:  W = W_bc; A = A_bc; Bm = B_bc; din = 128; break;
    case 1:  W = W_f0; A = A_f0; Bm = B_f0; din = 64;  break;
    case 2:  W = W_f1; A = A_f1; Bm = B_f1; din = 128; break;
    case 3:  W = W_f2; A = A_f2; Bm = B_f2; din = 128; break;
    case 4:  W = W_a0; A = A_a0; Bm = B_a0; din = 128; break;
    default: W = W_a1; A = A_a1; Bm = B_a1; din = 128; break;
  }
  if (e >= din * 128) return;
  const int k = e >> 7, n = e & 127;
  float wv = W[k * 128 + n];
  #pragma unroll
  for (int r = 0; r < 4; ++r)
    wv += A[(b * din + k) * 4 + r] * Bm[(b * 4 + r) * 128 + n];
  if (l == 1)      Wt0[(b * 128 + n) * 64  + k] = f2bfu(wv);
  else if (l == 2) Wt1[(b * 128 + n) * 128 + k] = f2bfu(wv * LN2);
  else if (l == 3) Wt2[(b * 128 + n) * 128 + k] = f2bfu(wv * LN2);
  else if (l == 0) Wbc[(b * 128 + k) * 128 + n] = wv;
  else if (l == 4) Wa0[(b * 128 + k) * 128 + n] = wv;
  else             Wa1[(b * 128 + k) * 128 + n] = wv;
}

// ---------------------------------------------------------------------------
// dense_ssp: out[row,n] = ssp(sum_k in[row,k]*W[b,k,n] + bias[n])
// ---------------------------------------------------------------------------
__global__ __launch_bounds__(512) void dense_ssp(
    const float* __restrict__ in, const float* __restrict__ W,
    const float* __restrict__ bias, float* __restrict__ out)
{
  __shared__ float in_l[4][128];
  const int t = threadIdx.x;
  const int rg0 = blockIdx.x << 2;
  const int b = rg0 >> 9;
  in_l[t >> 7][t & 127] = in[rg0 * 128 + t];
  __syncthreads();
  const int j = t >> 7, n = t & 127;
  const float* wp = W + (b << 14) + n;
  const float* ip = in_l[j];
  float acc = 0.f;
  #pragma unroll 8
  for (int k = 0; k < 128; ++k) acc += ip[k] * wp[k << 7];
  out[(rg0 + j) * 128 + n] = ssp_f(acc + bias[n]);
}

// ---------------------------------------------------------------------------
// dense2_ssp: fused final two atomwise layers.
// h = ssp(in @ W0 + b0); out = ssp(h @ W1 + b1) + resid
// ---------------------------------------------------------------------------
__global__ __launch_bounds__(512) void dense2_ssp(
    const float* __restrict__ in,
    const float* __restrict__ W0, const float* __restrict__ b0,
    const float* __restrict__ W1, const float* __restrict__ b1,
    const float* __restrict__ resid, float* __restrict__ out)
{
  __shared__ float in_l[4][128];
  __shared__ float h_l[4][128];
  const int t = threadIdx.x;
  const int rg0 = blockIdx.x << 2;
  const int b = rg0 >> 9;
  in_l[t >> 7][t & 127] = in[rg0 * 128 + t];
  __syncthreads();
  const int j = t >> 7, n = t & 127;
  {
    const float* wp = W0 + (b << 14) + n;
    const float* ip = in_l[j];
    float acc = 0.f;
    #pragma unroll 8
    for (int k = 0; k < 128; ++k) acc += ip[k] * wp[k << 7];
    h_l[j][n] = ssp_f(acc + b0[n]);
  }
  __syncthreads();
  {
    const float* wp = W1 + (b << 14) + n;
    const float* ip = h_l[j];
    float acc = 0.f;
    #pragma unroll 8
    for (int k = 0; k < 128; ++k) acc += ip[k] * wp[k << 7];
    const int oi = (rg0 + j) * 128 + n;
    out[oi] = ssp_f(acc + b1[n]) + resid[oi];
  }
}

// ---------------------------------------------------------------------------
// schnet_core: grid 1024 = b*512+i (one generation: 4 blocks/CU resident).
// 256 threads = 4 waves; wave w owns nout [w*32, w*32+32).
// Compacts all 512 j's; tiles of 64 rows, 16-row sub-tile pruning via uniform
// guards (jt*16 < na-jt0) with static unroll.
// Per tile: S pack->fbuf | B1 | next-f prefetch | G1(wfA) | issue wfB | E1->h |
//   B2 | G2(wfB) | B2' | issue wfC | E2->h | B3 | G3(wfC) | issue wfA' | E3.
// ---------------------------------------------------------------------------
__global__ __launch_bounds__(256, 4) void schnet_core(
    const float* __restrict__ f_ij, const float* __restrict__ c_ij,
    const int* __restrict__ mask,
    const unsigned short* __restrict__ Wt0, const unsigned short* __restrict__ Wt1,
    const unsigned short* __restrict__ Wt2,
    const float* __restrict__ bias0, const float* __restrict__ bias1,
    const float* __restrict__ bias2,
    const float* __restrict__ xi, float* __restrict__ y)
{
  __shared__ __align__(16) unsigned short fbuf[64 * 64];    // [j][k] bf16, 8-slot swz
  __shared__ __align__(16) unsigned short hbuf[64 * 128];   // h', 16-slot swz
  __shared__ int   jlist[576];
  __shared__ float slist[576];
  __shared__ float bias_l[384];          // 3x128: b*log2e - 1
  __shared__ int cnt_s[8], base_s[8], nact_s;

  const int tid  = threadIdx.x;
  const int lane = tid & 63;
  const int w    = tid >> 6;
  const int lrow = lane & 15;
  const int lgrp = lane >> 4;
  const int bi   = blockIdx.x;          // b*512 + i
  const int b    = bi >> 9;

  // ---- bias staging: pre-scaled so t = fma(acc, log2e, bpre); 0.5 folded ----
  for (int t = tid; t < 384; t += 256) {
    const float* bp = (t < 128) ? bias0 : (t < 256) ? bias1 : bias2;
    bias_l[t] = __builtin_fmaf(bp[t & 127], LOG2E, -1.0f);
  }

  // ---- deterministic compaction of all 512 j's (slist pre-scaled by ln2) ----
  const int mb = bi << 9;
  const int jA = tid, jB = tid + 256;
  const int   mA = mask[mb + jA]; const float cA = c_ij[mb + jA];
  const int   mB = mask[mb + jB]; const float cB = c_ij[mb + jB];
  unsigned long long balA = __ballot(mA != 0);
  unsigned long long balB = __ballot(mB != 0);
  if (lane == 0) { cnt_s[w] = __popcll(balA); cnt_s[4 + w] = __popcll(balB); }
  __syncthreads();
  if (tid == 0) {
    int s = 0;
    for (int c = 0; c < 8; ++c) { base_s[c] = s; s += cnt_s[c]; }
    nact_s = s;
  }
  __syncthreads();
  const int na = nact_s;
  const unsigned long long lm = (1ull << lane) - 1ull;
  if (mA) { int p = base_s[w]     + __popcll(balA & lm); jlist[p] = jA; slist[p] = cA * LN2; }
  if (mB) { int p = base_s[4 + w] + __popcll(balB & lm); jlist[p] = jB; slist[p] = cB * LN2; }
  if (tid < 64) { int idx = na + tid; if (idx < 576) { jlist[idx] = 0; slist[idx] = 0.f; } }
  __syncthreads();

  const int tiles = (na + 63) >> 6;

  const int mg = w;
  const float* fbase = f_ij + ((size_t)mb << 6);

  const int wbase0 = ((b << 7) + mg * 32 + lrow) * 64  + (lgrp << 3);
  const int wbase1 = ((b << 7) + mg * 32 + lrow) * 128 + (lgrp << 3);

  float accy[2][4] = {{0.f,0.f,0.f,0.f},{0.f,0.f,0.f,0.f}};

  // ---- initial wfA (G1 weights) ----
  bf16x8 wfA[2][2];
  {
    const unsigned short* wp = Wt0 + wbase0;
    #pragma unroll
    for (int nt = 0; nt < 2; ++nt)
      #pragma unroll
      for (int ks = 0; ks < 2; ++ks)
        wfA[nt][ks] = *(const bf16x8*)(wp + nt * (16 * 64) + ks * 32);
  }

  // ---- prefetch first f tile into regs ----
  const int r    = tid >> 2;
  const int part = tid & 3;
  f32x4 pre0, pre1, pre2, pre3;
  {
    const int ja = jlist[r];
    const f32x4* src = (const f32x4*)(fbase + ja * 64 + part * 16);
    pre0 = src[0]; pre1 = src[1]; pre2 = src[2]; pre3 = src[3];
  }

  for (int tt = 0; tt < tiles; ++tt) {
    const int jt0 = tt << 6;
    const int jcnt = na - jt0;          // rows remaining (uniform)

    // ---- S: pack prefetched regs -> fbuf ----
    {
      char* dst = (char*)fbuf + r * 128;
      const int o0 = (part * 32) ^ SWZF(r);
      *(u32x4*)(dst + o0)        = pack8(pre0, pre1);
      *(u32x4*)(dst + (o0 ^ 16)) = pack8(pre2, pre3);
    }
    __syncthreads();                    // B1: fbuf ready

    // ---- guarded next-f prefetch ----
    if (tt + 1 < tiles) {
      const int ja = jlist[((tt + 1) << 6) + r];
      const f32x4* src = (const f32x4*)(fbase + ja * 64 + part * 16);
      pre0 = src[0]; pre1 = src[1]; pre2 = src[2]; pre3 = src[3];
    }

    f32x4 acc[2][4];

    // ---- G1: h1^T = Wt0 * f^T (K=64) ----
    #pragma unroll
    for (int nt = 0; nt < 2; ++nt)
      #pragma unroll
      for (int jt = 0; jt < 4; ++jt) acc[nt][jt] = fzero4();
    #pragma unroll
    for (int jt = 0; jt < 4; ++jt) {
      if (jt * 16 < jcnt) {
        const int j = jt * 16 + lrow;
        const char* rb = (const char*)fbuf + j * 128;
        const int sw = SWZF(j);
        #pragma unroll
        for (int ks = 0; ks < 2; ++ks) {
          bf16x8 bf = *(const bf16x8*)(rb + ((lgrp * 16 + ks * 64) ^ sw));
          acc[0][jt] = __builtin_amdgcn_mfma_f32_16x16x32_bf16(wfA[0][ks], bf, acc[0][jt], 0, 0, 0);
          acc[1][jt] = __builtin_amdgcn_mfma_f32_16x16x32_bf16(wfA[1][ks], bf, acc[1][jt], 0, 0, 0);
        }
      }
    }

    // ---- issue wfB (G2 weights) ----
    bf16x8 wfB[2][4];
    {
      const unsigned short* wp = Wt1 + wbase1;
      asm volatile("" : "+v"(wp));
      #pragma unroll
      for (int nt = 0; nt < 2; ++nt)
        #pragma unroll
        for (int ks = 0; ks < 4; ++ks)
          wfB[nt][ks] = *(const bf16x8*)(wp + nt * (16 * 128) + ks * 32);
    }

    // ---- E1: h1' -> bf16 -> hbuf ----
    {
      f32x4 bp0 = *(const f32x4*)(bias_l + mg * 32 + 0  + lgrp * 4);
      f32x4 bp1 = *(const f32x4*)(bias_l + mg * 32 + 16 + lgrp * 4);
      #pragma unroll
      for (int jt = 0; jt < 4; ++jt) {
        if (jt * 16 < jcnt) {
          const int j = jt * 16 + lrow;
          char* rb = (char*)hbuf + j * 256;
          const int sw = SWZH(j);
          #pragma unroll
          for (int nt = 0; nt < 2; ++nt) {
            const int n0 = mg * 32 + nt * 16 + lgrp * 4;
            const f32x4 bp = nt ? bp1 : bp0;
            float e0 = ssp_pre(acc[nt][jt].x, bp.x);
            float e1 = ssp_pre(acc[nt][jt].y, bp.y);
            float e2 = ssp_pre(acc[nt][jt].z, bp.z);
            float e3 = ssp_pre(acc[nt][jt].w, bp.w);
            u32x2 pk;
            pk.x = (unsigned)f2bfu(e0) | ((unsigned)f2bfu(e1) << 16);
            pk.y = (unsigned)f2bfu(e2) | ((unsigned)f2bfu(e3) << 16);
            *(u32x2*)(rb + ((n0 * 2) ^ sw)) = pk;
          }
        }
      }
    }
    __syncthreads();                    // B2: h1 ready

    // ---- G2: h2^T = Wt1' * h1'^T (K=128) ----
    #pragma unroll
    for (int nt = 0; nt < 2; ++nt)
      #pragma unroll
      for (int jt = 0; jt < 4; ++jt) acc[nt][jt] = fzero4();
    #pragma unroll
    for (int jt = 0; jt < 4; ++jt) {
      if (jt * 16 < jcnt) {
        const int j = jt * 16 + lrow;
        const char* rb = (const char*)hbuf + j * 256;
        const int sw = SWZH(j);
        #pragma unroll
        for (int ks = 0; ks < 4; ++ks) {
          bf16x8 bf = *(const bf16x8*)(rb + ((lgrp * 16 + ks * 64) ^ sw));
          acc[0][jt] = __builtin_amdgcn_mfma_f32_16x16x32_bf16(wfB[0][ks], bf, acc[0][jt], 0, 0, 0);
          acc[1][jt] = __builtin_amdgcn_mfma_f32_16x16x32_bf16(wfB[1][ks], bf, acc[1][jt], 0, 0, 0);
        }
      }
    }
    __syncthreads();                    // B2': h1 readers done

    // ---- issue wfC (G3 weights) ----
    bf16x8 wfC[2][4];
    {
      const unsigned short* wp = Wt2 + wbase1;
      asm volatile("" : "+v"(wp));
      #pragma unroll
      for (int nt = 0; nt < 2; ++nt)
        #pragma unroll
        for (int ks = 0; ks < 4; ++ks)
          wfC[nt][ks] = *(const bf16x8*)(wp + nt * (16 * 128) + ks * 32);
    }

    // ---- E2: h2' -> bf16 -> hbuf ----
    {
      f32x4 bp0 = *(const f32x4*)(bias_l + 128 + mg * 32 + 0  + lgrp * 4);
      f32x4 bp1 = *(const f32x4*)(bias_l + 128 + mg * 32 + 16 + lgrp * 4);
      #pragma unroll
      for (int jt = 0; jt < 4; ++jt) {
        if (jt * 16 < jcnt) {
          const int j = jt * 16 + lrow;
          char* rb = (char*)hbuf + j * 256;
          const int sw = SWZH(j);
          #pragma unroll
          for (int nt = 0; nt < 2; ++nt) {
            const int n0 = mg * 32 + nt * 16 + lgrp * 4;
            const f32x4 bp = nt ? bp1 : bp0;
            float e0 = ssp_pre(acc[nt][jt].x, bp.x);
            float e1 = ssp_pre(acc[nt][jt].y, bp.y);
            float e2 = ssp_pre(acc[nt][jt].z, bp.z);
            float e3 = ssp_pre(acc[nt][jt].w, bp.w);
            u32x2 pk;
            pk.x = (unsigned)f2bfu(e0) | ((unsigned)f2bfu(e1) << 16);
            pk.y = (unsigned)f2bfu(e2) | ((unsigned)f2bfu(e3) << 16);
            *(u32x2*)(rb + ((n0 * 2) ^ sw)) = pk;
          }
        }
      }
    }
    __syncthreads();                    // B3: h2 ready

    // ---- G3: h3^T = Wt2' * h2'^T (K=128) ----
    #pragma unroll
    for (int nt = 0; nt < 2; ++nt)
      #pragma unroll
      for (int jt = 0; jt < 4; ++jt) acc[nt][jt] = fzero4();
    #pragma unroll
    for (int jt = 0; jt < 4; ++jt) {
      if (jt * 16 < jcnt) {
        const int j = jt * 16 + lrow;
        const char* rb = (const char*)hbuf + j * 256;
        const int sw = SWZH(j);
        #pragma unroll
        for (int ks = 0; ks < 4; ++ks) {
          bf16x8 bf = *(const bf16x8*)(rb + ((lgrp * 16 + ks * 64) ^ sw));
          acc[0][jt] = __builtin_amdgcn_mfma_f32_16x16x32_bf16(wfC[0][ks], bf, acc[0][jt], 0, 0, 0);
          acc[1][jt] = __builtin_amdgcn_mfma_f32_16x16x32_bf16(wfC[1][ks], bf, acc[1][jt], 0, 0, 0);
        }
      }
    }

    // ---- issue wfA' (next tile's G1 weights) ----
    {
      const unsigned short* wp = Wt0 + wbase0;
      asm volatile("" : "+v"(wp));
      #pragma unroll
      for (int nt = 0; nt < 2; ++nt)
        #pragma unroll
        for (int ks = 0; ks < 2; ++ks)
          wfA[nt][ks] = *(const bf16x8*)(wp + nt * (16 * 64) + ks * 32);
    }

    // ---- E3: h3' = log2-form; accy += (s*ln2) * xi[j,f] * h3' ----
    {
      f32x4 bp0 = *(const f32x4*)(bias_l + 256 + mg * 32 + 0  + lgrp * 4);
      f32x4 bp1 = *(const f32x4*)(bias_l + 256 + mg * 32 + 16 + lgrp * 4);
      #pragma unroll
      for (int jt = 0; jt < 4; ++jt) {
        if (jt * 16 < jcnt) {
          const int jj = jt * 16 + lrow;
          const float s  = slist[jt0 + jj];
          const int   ja = jlist[jt0 + jj];
          const float* xr = xi + (((b << 9) + ja) << 7);
          #pragma unroll
          for (int nt = 0; nt < 2; ++nt) {
            const int n0 = mg * 32 + nt * 16 + lgrp * 4;
            const f32x4 bp = nt ? bp1 : bp0;
            f32x4 xv = *(const f32x4*)(xr + n0);
            float h0 = ssp_pre(acc[nt][jt].x, bp.x);
            float h1 = ssp_pre(acc[nt][jt].y, bp.y);
            float h2 = ssp_pre(acc[nt][jt].z, bp.z);
            float h3 = ssp_pre(acc[nt][jt].w, bp.w);
            accy[nt][0] += s * xv.x * h0;
            accy[nt][1] += s * xv.y * h1;
            accy[nt][2] += s * xv.z * h2;
            accy[nt][3] += s * xv.w * h3;
          }
        }
      }
    }
    // no loop-end barrier: B1(t+1) orders G3/E3 reads vs next writes
  }

  // ---- reduce over the 16 j-sub-lanes; write y[b,i,:] ----
  #pragma unroll
  for (int d = 1; d < 16; d <<= 1)
    #pragma unroll
    for (int nt = 0; nt < 2; ++nt)
      #pragma unroll
      for (int rr = 0; rr < 4; ++rr)
        accy[nt][rr] += __shfl_xor(accy[nt][rr], d, 64);
  if (lrow == 0) {
    float* yo = y + ((size_t)bi << 7);
    #pragma unroll
    for (int nt = 0; nt < 2; ++nt) {
      const int n0 = mg * 32 + nt * 16 + lgrp * 4;
      f32x4 v = {accy[nt][0], accy[nt][1], accy[nt][2], accy[nt][3]};
      *(f32x4*)(yo + n0) = v;
    }
  }
}

// ---------------------------------------------------------------------------
extern "C" void kernel_launch(void* const* d_in, const int* in_sizes, int n_in,
                              void* d_out, int out_size, void* d_ws, size_t ws_size,
                              hipStream_t stream)
{
  const float* x    = (const float*)d_in[0];
  const float* f_ij = (const float*)d_in[1];
  const float* c_ij = (const float*)d_in[2];
  const int*   mask = (const int*)d_in[3];
  const float* W_bc = (const float*)d_in[4];
  const float* b_bc = (const float*)d_in[5];
  const float* A_bc = (const float*)d_in[6];
  const float* B_bc = (const float*)d_in[7];
  const float* W_f0 = (const float*)d_in[8];
  const float* b_f0 = (const float*)d_in[9];
  const float* A_f0 = (const float*)d_in[10];
  const float* B_f0 = (const float*)d_in[11];
  const float* W_f1 = (const float*)d_in[12];
  const float* b_f1 = (const float*)d_in[13];
  const float* A_f1 = (const float*)d_in[14];
  const float* B_f1 = (const float*)d_in[15];
  const float* W_f2 = (const float*)d_in[16];
  const float* b_f2 = (const float*)d_in[17];
  const float* A_f2 = (const float*)d_in[18];
  const float* B_f2 = (const float*)d_in[19];
  const float* W_a0 = (const float*)d_in[20];
  const float* b_a0 = (const float*)d_in[21];
  const float* A_a0 = (const float*)d_in[22];
  const float* B_a0 = (const float*)d_in[23];
  const float* W_a1 = (const float*)d_in[24];
  const float* b_a1 = (const float*)d_in[25];
  const float* A_a1 = (const float*)d_in[26];
  const float* B_a1 = (const float*)d_in[27];
  float* out = (float*)d_out;

  char* ws = (char*)d_ws;
  unsigned short* Wt0 = (unsigned short*)(ws);            //  32768 B
  unsigned short* Wt1 = (unsigned short*)(ws + 32768);    //  65536 B
  unsigned short* Wt2 = (unsigned short*)(ws + 98304);    //  65536 B
  float* Wbc = (float*)(ws + 163840);                     // 131072 B
  float* Wa0 = (float*)(ws + 294912);                     // 131072 B
  float* Wa1 = (float*)(ws + 425984);                     // 131072 B
  float* xi  = (float*)(ws + 557056);                     // 524288 B
  float* yp  = (float*)(ws + 1081344);                    // 524288 B (~1.6 MB total)

  prep_weights<<<dim3(64, 6, 2), 256, 0, stream>>>(
      W_bc, A_bc, B_bc, W_f0, A_f0, B_f0, W_f1, A_f1, B_f1,
      W_f2, A_f2, B_f2, W_a0, A_a0, B_a0, W_a1, A_a1, B_a1,
      Wt0, Wt1, Wt2, Wbc, Wa0, Wa1);

  dense_ssp<<<256, 512, 0, stream>>>(x, Wbc, b_bc, xi);

  schnet_core<<<1024, 256, 0, stream>>>(f_ij, c_ij, mask, Wt0, Wt1, Wt2,
                                        b_f0, b_f1, b_f2, xi, yp);

  dense2_ssp<<<256, 512, 0, stream>>>(yp, Wa0, b_a0, Wa1, b_a1, x, out);
}